// Round 16
// baseline (449.891 us; speedup 1.0000x reference)
//
#include <hip/hip_runtime.h>
#include <hip/hip_bf16.h>

#define Bn 4
#define Nn 1024
#define Dn 1024
#define Hn 16
#define DHn 64
#define INNERn 1024
#define SCALEf 0.125f

typedef unsigned short u16;
using bf16x8 = __attribute__((ext_vector_type(8))) short;
using f32x4  = __attribute__((ext_vector_type(4))) float;

__device__ __forceinline__ u16 f2bf(float f) {
    __hip_bfloat16 h = __float2bfloat16(f);
    return *(u16*)&h;
}
__device__ __forceinline__ float bf2f(u16 h) {
    union { unsigned int u; float f; } cv;
    cv.u = ((unsigned int)h) << 16;
    return cv.f;
}
// negate a bf16x8 by flipping sign bits
__device__ __forceinline__ bf16x8 bfneg(bf16x8 v) {
    bf16x8 r;
#pragma unroll
    for (int j = 0; j < 8; ++j) r[j] = (short)(v[j] ^ (short)0x8000);
    return r;
}
// XCD-aware bijective block remap (nwg % 8 == 0): groups cpx consecutive
// tiles onto one XCD so panel-sharing neighbors hit the same L2.
__device__ __forceinline__ int xcd_swz(int id, int nwg) {
    int cpx = nwg >> 3;
    return (id & 7) * cpx + (id >> 3);
}

#define MFMA16(acc, a, b) acc = __builtin_amdgcn_mfma_f32_16x16x32_bf16(a, b, acc, 0, 0, 0)

// ---------------------------------------------------------------------------
// Kernel 0: split fp32 arrays into (hi, lo) bf16 planes.  (unchanged)
// ---------------------------------------------------------------------------
__global__ __launch_bounds__(256) void split6(
    const float* __restrict__ x_re, const float* __restrict__ x_im,
    const float* __restrict__ wq_re, const float* __restrict__ wq_im,
    const float* __restrict__ wo_re, const float* __restrict__ wo_im,
    u16* __restrict__ xh_re, u16* __restrict__ xl_re,
    u16* __restrict__ xh_im, u16* __restrict__ xl_im,
    u16* __restrict__ wqh_re, u16* __restrict__ wql_re,
    u16* __restrict__ wqh_im, u16* __restrict__ wql_im,
    u16* __restrict__ woh_re, u16* __restrict__ wol_re,
    u16* __restrict__ woh_im, u16* __restrict__ wol_im)
{
    const float* in; u16* hi; u16* lo; size_t n;
    switch (blockIdx.y) {
        case 0:  in = x_re;  hi = xh_re;  lo = xl_re;  n = 4194304; break;
        case 1:  in = x_im;  hi = xh_im;  lo = xl_im;  n = 4194304; break;
        case 2:  in = wq_re; hi = wqh_re; lo = wql_re; n = 1048576; break;
        case 3:  in = wq_im; hi = wqh_im; lo = wql_im; n = 1048576; break;
        case 4:  in = wo_re; hi = woh_re; lo = wol_re; n = 1048576; break;
        default: in = wo_im; hi = woh_im; lo = wol_im; n = 1048576; break;
    }
    size_t i = ((size_t)blockIdx.x * 256 + threadIdx.x) * 8;
    if (i >= n) return;
    float4 f0 = *(const float4*)(in + i);
    float4 f1 = *(const float4*)(in + i + 4);
    float v[8] = {f0.x, f0.y, f0.z, f0.w, f1.x, f1.y, f1.z, f1.w};
    bf16x8 h8, l8;
#pragma unroll
    for (int j = 0; j < 8; ++j) {
        u16 hh = f2bf(v[j]);
        h8[j] = (short)hh;
        l8[j] = (short)f2bf(v[j] - bf2f(hh));
    }
    *(bf16x8*)(hi + i) = h8;
    *(bf16x8*)(lo + i) = l8;
}

// ---------------------------------------------------------------------------
// Kernel 1: complex NT GEMM via split-bf16 MFMA — R15: A-side LDS DELETED.
//  A-fragments read directly from global (per-lane rows, L2-hot: the 8
//  e0-blocks sharing an A-panel run consecutively on one XCD via swizzle).
//  LDS ops/iter 36 -> 24; LDS 61.4 -> 40 KB -> 3 blocks/CU (12 waves).
// ---------------------------------------------------------------------------
__global__ __launch_bounds__(256) void gemm_qkv_mfma(
    const u16* __restrict__ xh_re, const u16* __restrict__ xl_re,
    const u16* __restrict__ xh_im, const u16* __restrict__ xl_im,
    const u16* __restrict__ qh_re, const u16* __restrict__ ql_re,
    const u16* __restrict__ qh_im, const u16* __restrict__ ql_im,
    u16* __restrict__ w_re16, u16* __restrict__ w_im16)
{
    const int K = Dn;
    __shared__ __align__(16) u16 Bhr[128][40], Blr[128][40], Bhi[128][40], Bli[128][40];

    int t    = threadIdx.x;
    int lane = t & 63;
    int wv   = t >> 6;
    int lq   = lane & 15, qd = lane >> 4;
    int wr   = wv >> 1,   wc = wv & 1;

    int id  = blockIdx.y * 8 + blockIdx.x;
    int swz = xcd_swz(id, 512);
    int m0 = (swz >> 3) * 64;
    int e0 = (swz & 7) * 128;

    int br = t >> 1, bc = (t & 1) * 16;

    // A-fragment direct-global offsets (row = m0 + wr*32 + rf*16 + lq)
    size_t aoff0 = (size_t)(m0 + wr*32 + lq) * K + qd*8;
    size_t aoff1 = (size_t)(m0 + wr*32 + 16 + lq) * K + qd*8;

    const u16* pB0 = qh_re + (size_t)(e0 + br) * K + bc;
    const u16* pB1 = ql_re + (size_t)(e0 + br) * K + bc;
    const u16* pB2 = qh_im + (size_t)(e0 + br) * K + bc;
    const u16* pB3 = ql_im + (size_t)(e0 + br) * K + bc;

    f32x4 accR[2][4], accI[2][4];
#pragma unroll
    for (int i = 0; i < 2; ++i)
#pragma unroll
        for (int j = 0; j < 4; ++j) { accR[i][j] = (f32x4)0.f; accI[i][j] = (f32x4)0.f; }

    for (int k0 = 0; k0 < K; k0 += 32) {
        // ---- A fragments from global (issue early; L2-hot) ----
        bf16x8 Arh[2], Arl[2], Aih[2], Ail[2];
        Arh[0] = *(const bf16x8*)(xh_re + aoff0 + k0);
        Arh[1] = *(const bf16x8*)(xh_re + aoff1 + k0);
        Arl[0] = *(const bf16x8*)(xl_re + aoff0 + k0);
        Arl[1] = *(const bf16x8*)(xl_re + aoff1 + k0);
        Aih[0] = *(const bf16x8*)(xh_im + aoff0 + k0);
        Aih[1] = *(const bf16x8*)(xh_im + aoff1 + k0);
        Ail[0] = *(const bf16x8*)(xl_im + aoff0 + k0);
        Ail[1] = *(const bf16x8*)(xl_im + aoff1 + k0);
        // ---- B staging loads ----
        bf16x8 vb0a = *(const bf16x8*)(pB0 + k0), vb0b = *(const bf16x8*)(pB0 + k0 + 8);
        bf16x8 vb1a = *(const bf16x8*)(pB1 + k0), vb1b = *(const bf16x8*)(pB1 + k0 + 8);
        bf16x8 vb2a = *(const bf16x8*)(pB2 + k0), vb2b = *(const bf16x8*)(pB2 + k0 + 8);
        bf16x8 vb3a = *(const bf16x8*)(pB3 + k0), vb3b = *(const bf16x8*)(pB3 + k0 + 8);
        __syncthreads();
        *(bf16x8*)&Bhr[br][bc] = vb0a; *(bf16x8*)&Bhr[br][bc+8] = vb0b;
        *(bf16x8*)&Blr[br][bc] = vb1a; *(bf16x8*)&Blr[br][bc+8] = vb1b;
        *(bf16x8*)&Bhi[br][bc] = vb2a; *(bf16x8*)&Bhi[br][bc+8] = vb2b;
        *(bf16x8*)&Bli[br][bc] = vb3a; *(bf16x8*)&Bli[br][bc+8] = vb3b;
        __syncthreads();

        bf16x8 Anh[2], Anl[2];
#pragma unroll
        for (int rf = 0; rf < 2; ++rf) {
            Anh[rf] = bfneg(Aih[rf]);
            Anl[rf] = bfneg(Ail[rf]);
        }
#pragma unroll
        for (int cf = 0; cf < 4; ++cf) {
            int col = wc*64 + cf*16 + lq;
            bf16x8 Brh = *(const bf16x8*)&Bhr[col][qd*8];
            bf16x8 Brl = *(const bf16x8*)&Blr[col][qd*8];
            bf16x8 Bih = *(const bf16x8*)&Bhi[col][qd*8];
            bf16x8 Bil = *(const bf16x8*)&Bli[col][qd*8];
#pragma unroll
            for (int rf = 0; rf < 2; ++rf) {
                MFMA16(accR[rf][cf], Arh[rf], Brh);
                MFMA16(accR[rf][cf], Arh[rf], Brl);
                MFMA16(accR[rf][cf], Arl[rf], Brh);
                MFMA16(accR[rf][cf], Anh[rf], Bih);
                MFMA16(accR[rf][cf], Anh[rf], Bil);
                MFMA16(accR[rf][cf], Anl[rf], Bih);
                MFMA16(accI[rf][cf], Arh[rf], Bih);
                MFMA16(accI[rf][cf], Arh[rf], Bil);
                MFMA16(accI[rf][cf], Arl[rf], Bih);
                MFMA16(accI[rf][cf], Aih[rf], Brh);
                MFMA16(accI[rf][cf], Aih[rf], Brl);
                MFMA16(accI[rf][cf], Ail[rf], Brh);
            }
        }
    }

#pragma unroll
    for (int rf = 0; rf < 2; ++rf)
#pragma unroll
        for (int cf = 0; cf < 4; ++cf)
#pragma unroll
            for (int p = 0; p < 4; ++p) {
                int m = m0 + wr*32 + rf*16 + qd*4 + p;
                int e = e0 + wc*64 + cf*16 + lq;
                int b = m >> 10, n = m & 1023;
                int h = e >> 6,  dh = e & 63;
                size_t idx = ((size_t)(b*Hn + h) * Nn + n) * DHn + dh;
                w_re16[idx] = f2bf(accR[rf][cf][p]);
                w_im16[idx] = f2bf(accI[rf][cf][p]);
            }
}

// ---------------------------------------------------------------------------
// Kernel 2: MFMA flash attention — R14-verified (170 us), unchanged.
// ---------------------------------------------------------------------------
__global__ __launch_bounds__(256, 4) void attn_mfma(
    const u16* __restrict__ w_re16, const u16* __restrict__ w_im16,
    u16* __restrict__ ah_re, u16* __restrict__ al_re,
    u16* __restrict__ ah_im, u16* __restrict__ al_im)
{
    __shared__ __align__(16) u16 Kr[32][72], Ki[32][72];     //  9.2 KB
    __shared__ __align__(16) u16 Ktr[64][40], Kti[64][40];   // 10.2 KB
    __shared__ __align__(16) u16 Pr[64][40], Pi[64][40];     // 10.2 KB

    int t    = threadIdx.x;
    int lane = t & 63;
    int wv   = t >> 6;
    int lq   = lane & 15;
    int qd   = lane >> 4;
    int r0   = wv * 16;

    int id  = blockIdx.y * 16 + blockIdx.x;
    int swz = xcd_swz(id, 1024);
    int n0 = (swz & 15) * 64;
    int bh = swz >> 4;
    int b  = bh >> 4, h = bh & 15;
    const u16* wr = w_re16 + (size_t)bh * (Nn*DHn);
    const u16* wi = w_im16 + (size_t)bh * (Nn*DHn);

    // ---- Q fragments directly from global ----
    bf16x8 qfr[2], qfi[2], qfn[2];
    {
        const u16* qr = wr + (size_t)(n0 + r0 + lq) * DHn + qd*8;
        const u16* qi = wi + (size_t)(n0 + r0 + lq) * DHn + qd*8;
#pragma unroll
        for (int c = 0; c < 2; ++c) {
            qfr[c] = *(const bf16x8*)(qr + c*32);
            qfi[c] = *(const bf16x8*)(qi + c*32);
            qfn[c] = bfneg(qfr[c]);
        }
    }

    float rm[4], rl[4];
#pragma unroll
    for (int p = 0; p < 4; ++p) { rm[p] = -1e30f; rl[p] = 0.f; }
    f32x4 Ore[4], Oim[4];
#pragma unroll
    for (int d = 0; d < 4; ++d) { Ore[d] = (f32x4)0.f; Oim[d] = (f32x4)0.f; }

    int sm = t >> 3, sdc = (t & 7) * 8;
    int gdh = t & 63, gmc = t >> 6;

    for (int kt = 0; kt < Nn/32; ++kt) {
        __syncthreads();
        {
            const u16* pr = wr + (size_t)(kt*32 + sm) * DHn + sdc;
            const u16* pi = wi + (size_t)(kt*32 + sm) * DHn + sdc;
            *(bf16x8*)&Kr[sm][sdc] = *(const bf16x8*)pr;
            *(bf16x8*)&Ki[sm][sdc] = *(const bf16x8*)pi;
        }
        {
            const u16* gr = wr + (size_t)(kt*32 + gmc*8) * DHn + gdh;
            const u16* gi = wi + (size_t)(kt*32 + gmc*8) * DHn + gdh;
            bf16x8 tr, ti;
#pragma unroll
            for (int j = 0; j < 8; ++j) {
                tr[j] = (short)gr[(size_t)j * DHn];
                ti[j] = (short)gi[(size_t)j * DHn];
            }
            *(bf16x8*)&Ktr[gdh][gmc*8] = tr;
            *(bf16x8*)&Kti[gdh][gmc*8] = ti;
        }
        __syncthreads();

        float sre[2][4], sim[2][4], mag[2][4];
#pragma unroll
        for (int ct = 0; ct < 2; ++ct) {
            bf16x8 bkr[2], bki[2];
#pragma unroll
            for (int c = 0; c < 2; ++c) {
                bkr[c] = *(const bf16x8*)&Kr[ct*16 + lq][c*32 + qd*8];
                bki[c] = *(const bf16x8*)&Ki[ct*16 + lq][c*32 + qd*8];
            }
            f32x4 are = (f32x4)0.f, aim = (f32x4)0.f;
            __builtin_amdgcn_s_setprio(1);
            are = __builtin_amdgcn_mfma_f32_16x16x32_bf16(qfr[0], bkr[0], are, 0,0,0);
            are = __builtin_amdgcn_mfma_f32_16x16x32_bf16(qfi[0], bki[0], are, 0,0,0);
            are = __builtin_amdgcn_mfma_f32_16x16x32_bf16(qfr[1], bkr[1], are, 0,0,0);
            are = __builtin_amdgcn_mfma_f32_16x16x32_bf16(qfi[1], bki[1], are, 0,0,0);
            aim = __builtin_amdgcn_mfma_f32_16x16x32_bf16(qfi[0], bkr[0], aim, 0,0,0);
            aim = __builtin_amdgcn_mfma_f32_16x16x32_bf16(qfn[0], bki[0], aim, 0,0,0);
            aim = __builtin_amdgcn_mfma_f32_16x16x32_bf16(qfi[1], bkr[1], aim, 0,0,0);
            aim = __builtin_amdgcn_mfma_f32_16x16x32_bf16(qfn[1], bki[1], aim, 0,0,0);
            __builtin_amdgcn_s_setprio(0);
#pragma unroll
            for (int p = 0; p < 4; ++p) {
                float r = are[p] * SCALEf;
                float i = aim[p] * SCALEf;
                sre[ct][p] = r; sim[ct][p] = i;
                mag[ct][p] = sqrtf(r*r + i*i);
            }
        }

        float alpha[4];
#pragma unroll
        for (int p = 0; p < 4; ++p) {
            float pm = fmaxf(mag[0][p], mag[1][p]);
            pm = fmaxf(pm, __shfl_xor(pm, 1));
            pm = fmaxf(pm, __shfl_xor(pm, 2));
            pm = fmaxf(pm, __shfl_xor(pm, 4));
            pm = fmaxf(pm, __shfl_xor(pm, 8));
            float grow = pm - rm[p];
            if (grow > 8.f) {
                alpha[p] = __expf(-grow);
                rm[p] = pm;
            } else {
                alpha[p] = 1.f;
            }
        }
#pragma unroll
        for (int p = 0; p < 4; ++p) {
            float s = 0.f;
            int q = r0 + qd*4 + p;
#pragma unroll
            for (int ct = 0; ct < 2; ++ct) {
                float mg = mag[ct][p];
                float e = __expf(mg - rm[p]);
                s += e;
                float cr, ci;
                if (mg > 0.f) {
                    float f = e * __builtin_amdgcn_rcpf(mg);
                    cr = sre[ct][p] * f; ci = sim[ct][p] * f;
                } else { cr = e; ci = 0.f; }
                Pr[q][ct*16 + lq] = f2bf(cr);
                Pi[q][ct*16 + lq] = f2bf(ci);
            }
            s += __shfl_xor(s, 1);
            s += __shfl_xor(s, 2);
            s += __shfl_xor(s, 4);
            s += __shfl_xor(s, 8);
            rl[p] = rl[p]*alpha[p] + s;
        }

        if (alpha[0] != 1.f || alpha[1] != 1.f || alpha[2] != 1.f || alpha[3] != 1.f) {
#pragma unroll
            for (int d = 0; d < 4; ++d)
#pragma unroll
                for (int p = 0; p < 4; ++p) {
                    Ore[d][p] *= alpha[p];
                    Oim[d][p] *= alpha[p];
                }
        }

        bf16x8 par = *(const bf16x8*)&Pr[r0 + lq][qd*8];
        bf16x8 pai = *(const bf16x8*)&Pi[r0 + lq][qd*8];
        bf16x8 pan = bfneg(pai);
        __builtin_amdgcn_s_setprio(1);
#pragma unroll
        for (int d = 0; d < 4; ++d) {
            bf16x8 fr = *(const bf16x8*)&Ktr[d*16 + lq][qd*8];
            bf16x8 fi = *(const bf16x8*)&Kti[d*16 + lq][qd*8];
            Ore[d] = __builtin_amdgcn_mfma_f32_16x16x32_bf16(par, fr, Ore[d], 0,0,0);
            Ore[d] = __builtin_amdgcn_mfma_f32_16x16x32_bf16(pan, fi, Ore[d], 0,0,0);
            Oim[d] = __builtin_amdgcn_mfma_f32_16x16x32_bf16(par, fi, Oim[d], 0,0,0);
            Oim[d] = __builtin_amdgcn_mfma_f32_16x16x32_bf16(pai, fr, Oim[d], 0,0,0);
        }
        __builtin_amdgcn_s_setprio(0);
    }

#pragma unroll
    for (int p = 0; p < 4; ++p) {
        float inv = 1.f / rl[p];
        int n = n0 + r0 + qd*4 + p;
#pragma unroll
        for (int d = 0; d < 4; ++d) {
            int dh = d*16 + lq;
            size_t idx = ((size_t)b*Nn + n) * INNERn + h*DHn + dh;
            float vr = Ore[d][p] * inv;
            float vi = Oim[d][p] * inv;
            u16 hr = f2bf(vr);
            u16 hm = f2bf(vi);
            ah_re[idx] = hr; al_re[idx] = f2bf(vr - bf2f(hr));
            ah_im[idx] = hm; al_im[idx] = f2bf(vi - bf2f(hm));
        }
    }
}

// ---------------------------------------------------------------------------
// Kernel 3: output projection (real only) — R15: A-side LDS deleted (same
// transformation as gemm_qkv). LDS 40 KB -> 3 blocks/CU.
// ---------------------------------------------------------------------------
__global__ __launch_bounds__(256) void gemm_out_mfma(
    const u16* __restrict__ ah_re, const u16* __restrict__ al_re,
    const u16* __restrict__ ah_im, const u16* __restrict__ al_im,
    const u16* __restrict__ oh_re, const u16* __restrict__ ol_re,
    const u16* __restrict__ oh_im, const u16* __restrict__ ol_im,
    const float* __restrict__ b_re, float* __restrict__ out)
{
    const int K = INNERn;
    __shared__ __align__(16) u16 Bhr[128][40], Blr[128][40], Bhi[128][40], Bli[128][40];

    int t    = threadIdx.x;
    int lane = t & 63;
    int wv   = t >> 6;
    int lq   = lane & 15, qd = lane >> 4;
    int wr   = wv >> 1,   wc = wv & 1;

    int id  = blockIdx.y * 8 + blockIdx.x;
    int swz = xcd_swz(id, 512);
    int m0 = (swz >> 3) * 64;
    int d0 = (swz & 7) * 128;

    int br = t >> 1, bc = (t & 1) * 16;

    size_t aoff0 = (size_t)(m0 + wr*32 + lq) * K + qd*8;
    size_t aoff1 = (size_t)(m0 + wr*32 + 16 + lq) * K + qd*8;

    const u16* pB0 = oh_re + (size_t)(d0 + br) * K + bc;
    const u16* pB1 = ol_re + (size_t)(d0 + br) * K + bc;
    const u16* pB2 = oh_im + (size_t)(d0 + br) * K + bc;
    const u16* pB3 = ol_im + (size_t)(d0 + br) * K + bc;

    f32x4 accR[2][4];
#pragma unroll
    for (int i = 0; i < 2; ++i)
#pragma unroll
        for (int j = 0; j < 4; ++j) accR[i][j] = (f32x4)0.f;

    for (int k0 = 0; k0 < K; k0 += 32) {
        // ---- A fragments from global ----
        bf16x8 Arh[2], Arl[2], Aih[2], Ail[2];
        Arh[0] = *(const bf16x8*)(ah_re + aoff0 + k0);
        Arh[1] = *(const bf16x8*)(ah_re + aoff1 + k0);
        Arl[0] = *(const bf16x8*)(al_re + aoff0 + k0);
        Arl[1] = *(const bf16x8*)(al_re + aoff1 + k0);
        Aih[0] = *(const bf16x8*)(ah_im + aoff0 + k0);
        Aih[1] = *(const bf16x8*)(ah_im + aoff1 + k0);
        Ail[0] = *(const bf16x8*)(al_im + aoff0 + k0);
        Ail[1] = *(const bf16x8*)(al_im + aoff1 + k0);
        // ---- B staging loads ----
        bf16x8 vb0a = *(const bf16x8*)(pB0 + k0), vb0b = *(const bf16x8*)(pB0 + k0 + 8);
        bf16x8 vb1a = *(const bf16x8*)(pB1 + k0), vb1b = *(const bf16x8*)(pB1 + k0 + 8);
        bf16x8 vb2a = *(const bf16x8*)(pB2 + k0), vb2b = *(const bf16x8*)(pB2 + k0 + 8);
        bf16x8 vb3a = *(const bf16x8*)(pB3 + k0), vb3b = *(const bf16x8*)(pB3 + k0 + 8);
        __syncthreads();
        *(bf16x8*)&Bhr[br][bc] = vb0a; *(bf16x8*)&Bhr[br][bc+8] = vb0b;
        *(bf16x8*)&Blr[br][bc] = vb1a; *(bf16x8*)&Blr[br][bc+8] = vb1b;
        *(bf16x8*)&Bhi[br][bc] = vb2a; *(bf16x8*)&Bhi[br][bc+8] = vb2b;
        *(bf16x8*)&Bli[br][bc] = vb3a; *(bf16x8*)&Bli[br][bc+8] = vb3b;
        __syncthreads();

        bf16x8 Anh[2], Anl[2];
#pragma unroll
        for (int rf = 0; rf < 2; ++rf) {
            Anh[rf] = bfneg(Aih[rf]);
            Anl[rf] = bfneg(Ail[rf]);
        }
#pragma unroll
        for (int cf = 0; cf < 4; ++cf) {
            int col = wc*64 + cf*16 + lq;
            bf16x8 Brh = *(const bf16x8*)&Bhr[col][qd*8];
            bf16x8 Brl = *(const bf16x8*)&Blr[col][qd*8];
            bf16x8 Bih = *(const bf16x8*)&Bhi[col][qd*8];
            bf16x8 Bil = *(const bf16x8*)&Bli[col][qd*8];
#pragma unroll
            for (int rf = 0; rf < 2; ++rf) {
                MFMA16(accR[rf][cf], Arh[rf], Brh);
                MFMA16(accR[rf][cf], Arh[rf], Brl);
                MFMA16(accR[rf][cf], Arl[rf], Brh);
                MFMA16(accR[rf][cf], Anh[rf], Bih);
                MFMA16(accR[rf][cf], Anh[rf], Bil);
                MFMA16(accR[rf][cf], Anl[rf], Bih);
            }
        }
    }

#pragma unroll
    for (int rf = 0; rf < 2; ++rf)
#pragma unroll
        for (int cf = 0; cf < 4; ++cf)
#pragma unroll
            for (int p = 0; p < 4; ++p) {
                int m = m0 + wr*32 + rf*16 + qd*4 + p;
                int d = d0 + wc*64 + cf*16 + lq;
                out[(size_t)m * Dn + d] = accR[rf][cf][p] + b_re[d];
            }
}

// ---------------------------------------------------------------------------
// Workspace layout (u16 units), 64 MB total (unchanged).
// ---------------------------------------------------------------------------
extern "C" void kernel_launch(void* const* d_in, const int* in_sizes, int n_in,
                              void* d_out, int out_size, void* d_ws, size_t ws_size,
                              hipStream_t stream) {
    const float* x_re  = (const float*)d_in[0];
    const float* x_im  = (const float*)d_in[1];
    const float* wq_re = (const float*)d_in[2];
    const float* wq_im = (const float*)d_in[3];
    const float* wo_re = (const float*)d_in[4];
    const float* wo_im = (const float*)d_in[5];
    const float* bo_re = (const float*)d_in[6];

    const size_t M4 = (size_t)Bn * Nn * INNERn;   // 4M
    const size_t M1 = (size_t)INNERn * Dn;        // 1M

    u16* ws = (u16*)d_ws;
    u16* xh_re = ws;
    u16* xl_re = ws + M4;
    u16* xh_im = ws + 2*M4;
    u16* xl_im = ws + 3*M4;
    u16* wqh_re = ws + 4*M4;
    u16* wql_re = wqh_re + M1;
    u16* wqh_im = wql_re + M1;
    u16* wql_im = wqh_im + M1;
    u16* woh_re = wql_im + M1;
    u16* wol_re = woh_re + M1;
    u16* woh_im = wol_re + M1;
    u16* wol_im = woh_im + M1;
    u16* w_re16 = wol_im + M1;
    u16* w_im16 = w_re16 + M4;
    // attn output aliases the (dead after gemm_qkv) x hi/lo region
    u16* ah_re = xh_re;
    u16* al_re = xl_re;
    u16* ah_im = xh_im;
    u16* al_im = xl_im;

    {
        dim3 grid(2048, 6);
        split6<<<grid, 256, 0, stream>>>(x_re, x_im, wq_re, wq_im, wo_re, wo_im,
            xh_re, xl_re, xh_im, xl_im,
            wqh_re, wql_re, wqh_im, wql_im,
            woh_re, wol_re, woh_im, wol_im);
    }
    {
        dim3 grid(INNERn / 128, (Bn * Nn) / 64);
        gemm_qkv_mfma<<<grid, 256, 0, stream>>>(
            xh_re, xl_re, xh_im, xl_im,
            wqh_re, wql_re, wqh_im, wql_im,
            w_re16, w_im16);
    }
    {
        dim3 grid(Nn / 64, Bn * Hn);
        attn_mfma<<<grid, 256, 0, stream>>>(w_re16, w_im16,
                                            ah_re, al_re, ah_im, al_im);
    }
    {
        dim3 grid(Dn / 128, (Bn * Nn) / 64);
        gemm_out_mfma<<<grid, 256, 0, stream>>>(
            ah_re, al_re, ah_im, al_im,
            woh_re, wol_re, woh_im, wol_im,
            bo_re, (float*)d_out);
    }
}

// Round 20
// 406.963 us; speedup vs baseline: 1.1055x; 1.1055x over previous
//
#include <hip/hip_runtime.h>
#include <hip/hip_bf16.h>

#define Bn 4
#define Nn 1024
#define Dn 1024
#define Hn 16
#define DHn 64
#define INNERn 1024
#define SCALEf 0.125f

typedef unsigned short u16;
using bf16x8 = __attribute__((ext_vector_type(8))) short;
using f32x4  = __attribute__((ext_vector_type(4))) float;

__device__ __forceinline__ u16 f2bf(float f) {
    __hip_bfloat16 h = __float2bfloat16(f);
    return *(u16*)&h;
}
__device__ __forceinline__ float bf2f(u16 h) {
    union { unsigned int u; float f; } cv;
    cv.u = ((unsigned int)h) << 16;
    return cv.f;
}
// negate a bf16x8 by flipping sign bits
__device__ __forceinline__ bf16x8 bfneg(bf16x8 v) {
    bf16x8 r;
#pragma unroll
    for (int j = 0; j < 8; ++j) r[j] = (short)(v[j] ^ (short)0x8000);
    return r;
}
// XCD-aware bijective block remap (nwg % 8 == 0)
__device__ __forceinline__ int xcd_swz(int id, int nwg) {
    int cpx = nwg >> 3;
    return (id & 7) * cpx + (id >> 3);
}

#define MFMA16(acc, a, b) acc = __builtin_amdgcn_mfma_f32_16x16x32_bf16(a, b, acc, 0, 0, 0)

// ---------------------------------------------------------------------------
// Kernel 0: split fp32 arrays into (hi, lo) bf16 planes.  (unchanged)
// ---------------------------------------------------------------------------
__global__ __launch_bounds__(256) void split6(
    const float* __restrict__ x_re, const float* __restrict__ x_im,
    const float* __restrict__ wq_re, const float* __restrict__ wq_im,
    const float* __restrict__ wo_re, const float* __restrict__ wo_im,
    u16* __restrict__ xh_re, u16* __restrict__ xl_re,
    u16* __restrict__ xh_im, u16* __restrict__ xl_im,
    u16* __restrict__ wqh_re, u16* __restrict__ wql_re,
    u16* __restrict__ wqh_im, u16* __restrict__ wql_im,
    u16* __restrict__ woh_re, u16* __restrict__ wol_re,
    u16* __restrict__ woh_im, u16* __restrict__ wol_im)
{
    const float* in; u16* hi; u16* lo; size_t n;
    switch (blockIdx.y) {
        case 0:  in = x_re;  hi = xh_re;  lo = xl_re;  n = 4194304; break;
        case 1:  in = x_im;  hi = xh_im;  lo = xl_im;  n = 4194304; break;
        case 2:  in = wq_re; hi = wqh_re; lo = wql_re; n = 1048576; break;
        case 3:  in = wq_im; hi = wqh_im; lo = wql_im; n = 1048576; break;
        case 4:  in = wo_re; hi = woh_re; lo = wol_re; n = 1048576; break;
        default: in = wo_im; hi = woh_im; lo = wol_im; n = 1048576; break;
    }
    size_t i = ((size_t)blockIdx.x * 256 + threadIdx.x) * 8;
    if (i >= n) return;
    float4 f0 = *(const float4*)(in + i);
    float4 f1 = *(const float4*)(in + i + 4);
    float v[8] = {f0.x, f0.y, f0.z, f0.w, f1.x, f1.y, f1.z, f1.w};
    bf16x8 h8, l8;
#pragma unroll
    for (int j = 0; j < 8; ++j) {
        u16 hh = f2bf(v[j]);
        h8[j] = (short)hh;
        l8[j] = (short)f2bf(v[j] - bf2f(hh));
    }
    *(bf16x8*)(hi + i) = h8;
    *(bf16x8*)(lo + i) = l8;
}

// ---------------------------------------------------------------------------
// Kernel 1: complex NT GEMM via split-bf16 MFMA.  (R12/R14-verified)
// ---------------------------------------------------------------------------
__global__ __launch_bounds__(256) void gemm_qkv_mfma(
    const u16* __restrict__ xh_re, const u16* __restrict__ xl_re,
    const u16* __restrict__ xh_im, const u16* __restrict__ xl_im,
    const u16* __restrict__ qh_re, const u16* __restrict__ ql_re,
    const u16* __restrict__ qh_im, const u16* __restrict__ ql_im,
    u16* __restrict__ w_re16, u16* __restrict__ w_im16)
{
    const int K = Dn;
    __shared__ __align__(16) u16 Ahr[64][40], Alr[64][40], Ahi[64][40], Ali[64][40];
    __shared__ __align__(16) u16 Bhr[128][40], Blr[128][40], Bhi[128][40], Bli[128][40];

    int t    = threadIdx.x;
    int lane = t & 63;
    int wv   = t >> 6;
    int lq   = lane & 15, qd = lane >> 4;
    int wr   = wv >> 1,   wc = wv & 1;

    int id  = blockIdx.y * 8 + blockIdx.x;
    int swz = xcd_swz(id, 512);
    int m0 = (swz >> 3) * 64;
    int e0 = (swz & 7) * 128;

    int ar = t >> 2, ac = (t & 3) * 8;
    int br = t >> 1, bc = (t & 1) * 16;

    const u16* pA0 = xh_re + (size_t)(m0 + ar) * K + ac;
    const u16* pA1 = xl_re + (size_t)(m0 + ar) * K + ac;
    const u16* pA2 = xh_im + (size_t)(m0 + ar) * K + ac;
    const u16* pA3 = xl_im + (size_t)(m0 + ar) * K + ac;
    const u16* pB0 = qh_re + (size_t)(e0 + br) * K + bc;
    const u16* pB1 = ql_re + (size_t)(e0 + br) * K + bc;
    const u16* pB2 = qh_im + (size_t)(e0 + br) * K + bc;
    const u16* pB3 = ql_im + (size_t)(e0 + br) * K + bc;

    f32x4 accR[2][4], accI[2][4];
#pragma unroll
    for (int i = 0; i < 2; ++i)
#pragma unroll
        for (int j = 0; j < 4; ++j) { accR[i][j] = (f32x4)0.f; accI[i][j] = (f32x4)0.f; }

    for (int k0 = 0; k0 < K; k0 += 32) {
        bf16x8 va0 = *(const bf16x8*)(pA0 + k0);
        bf16x8 va1 = *(const bf16x8*)(pA1 + k0);
        bf16x8 va2 = *(const bf16x8*)(pA2 + k0);
        bf16x8 va3 = *(const bf16x8*)(pA3 + k0);
        bf16x8 vb0a = *(const bf16x8*)(pB0 + k0), vb0b = *(const bf16x8*)(pB0 + k0 + 8);
        bf16x8 vb1a = *(const bf16x8*)(pB1 + k0), vb1b = *(const bf16x8*)(pB1 + k0 + 8);
        bf16x8 vb2a = *(const bf16x8*)(pB2 + k0), vb2b = *(const bf16x8*)(pB2 + k0 + 8);
        bf16x8 vb3a = *(const bf16x8*)(pB3 + k0), vb3b = *(const bf16x8*)(pB3 + k0 + 8);
        __syncthreads();
        *(bf16x8*)&Ahr[ar][ac] = va0;
        *(bf16x8*)&Alr[ar][ac] = va1;
        *(bf16x8*)&Ahi[ar][ac] = va2;
        *(bf16x8*)&Ali[ar][ac] = va3;
        *(bf16x8*)&Bhr[br][bc] = vb0a; *(bf16x8*)&Bhr[br][bc+8] = vb0b;
        *(bf16x8*)&Blr[br][bc] = vb1a; *(bf16x8*)&Blr[br][bc+8] = vb1b;
        *(bf16x8*)&Bhi[br][bc] = vb2a; *(bf16x8*)&Bhi[br][bc+8] = vb2b;
        *(bf16x8*)&Bli[br][bc] = vb3a; *(bf16x8*)&Bli[br][bc+8] = vb3b;
        __syncthreads();

        bf16x8 Arh[2], Arl[2], Aih[2], Ail[2], Anh[2], Anl[2];
#pragma unroll
        for (int rf = 0; rf < 2; ++rf) {
            int row = wr*32 + rf*16 + lq;
            Arh[rf] = *(const bf16x8*)&Ahr[row][qd*8];
            Arl[rf] = *(const bf16x8*)&Alr[row][qd*8];
            Aih[rf] = *(const bf16x8*)&Ahi[row][qd*8];
            Ail[rf] = *(const bf16x8*)&Ali[row][qd*8];
            Anh[rf] = bfneg(Aih[rf]);
            Anl[rf] = bfneg(Ail[rf]);
        }
#pragma unroll
        for (int cf = 0; cf < 4; ++cf) {
            int col = wc*64 + cf*16 + lq;
            bf16x8 Brh = *(const bf16x8*)&Bhr[col][qd*8];
            bf16x8 Brl = *(const bf16x8*)&Blr[col][qd*8];
            bf16x8 Bih = *(const bf16x8*)&Bhi[col][qd*8];
            bf16x8 Bil = *(const bf16x8*)&Bli[col][qd*8];
#pragma unroll
            for (int rf = 0; rf < 2; ++rf) {
                MFMA16(accR[rf][cf], Arh[rf], Brh);
                MFMA16(accR[rf][cf], Arh[rf], Brl);
                MFMA16(accR[rf][cf], Arl[rf], Brh);
                MFMA16(accR[rf][cf], Anh[rf], Bih);
                MFMA16(accR[rf][cf], Anh[rf], Bil);
                MFMA16(accR[rf][cf], Anl[rf], Bih);
                MFMA16(accI[rf][cf], Arh[rf], Bih);
                MFMA16(accI[rf][cf], Arh[rf], Bil);
                MFMA16(accI[rf][cf], Arl[rf], Bih);
                MFMA16(accI[rf][cf], Aih[rf], Brh);
                MFMA16(accI[rf][cf], Aih[rf], Brl);
                MFMA16(accI[rf][cf], Ail[rf], Brh);
            }
        }
    }

#pragma unroll
    for (int rf = 0; rf < 2; ++rf)
#pragma unroll
        for (int cf = 0; cf < 4; ++cf)
#pragma unroll
            for (int p = 0; p < 4; ++p) {
                int m = m0 + wr*32 + rf*16 + qd*4 + p;
                int e = e0 + wc*64 + cf*16 + lq;
                int b = m >> 10, n = m & 1023;
                int h = e >> 6,  dh = e & 63;
                size_t idx = ((size_t)(b*Hn + h) * Nn + n) * DHn + dh;
                w_re16[idx] = f2bf(accR[rf][cf][p]);
                w_im16[idx] = f2bf(accI[rf][cf][p]);
            }
}

// ---------------------------------------------------------------------------
// Kernel 2: MFMA flash attention — R18: R14 structure + RESTORED P-visibility
// barrier (R17's replay-divergence traced to the compiler-ordered cross-lane
// ds_write->ds_read P dependency; barrier makes it architecturally safe).
// ---------------------------------------------------------------------------
__global__ __launch_bounds__(256, 4) void attn_mfma(
    const u16* __restrict__ w_re16, const u16* __restrict__ w_im16,
    u16* __restrict__ ah_re, u16* __restrict__ al_re,
    u16* __restrict__ ah_im, u16* __restrict__ al_im)
{
    __shared__ __align__(16) u16 Kr[32][72], Ki[32][72];     //  9.2 KB
    __shared__ __align__(16) u16 Ktr[64][40], Kti[64][40];   // 10.2 KB
    __shared__ __align__(16) u16 Pr[64][40], Pi[64][40];     // 10.2 KB

    int t    = threadIdx.x;
    int lane = t & 63;
    int wv   = t >> 6;
    int lq   = lane & 15;
    int qd   = lane >> 4;
    int r0   = wv * 16;

    int id  = blockIdx.y * 16 + blockIdx.x;
    int swz = xcd_swz(id, 1024);
    int n0 = (swz & 15) * 64;
    int bh = swz >> 4;
    int b  = bh >> 4, h = bh & 15;
    const u16* wr = w_re16 + (size_t)bh * (Nn*DHn);
    const u16* wi = w_im16 + (size_t)bh * (Nn*DHn);

    // ---- Q fragments directly from global ----
    bf16x8 qfr[2], qfi[2], qfn[2];
    {
        const u16* qr = wr + (size_t)(n0 + r0 + lq) * DHn + qd*8;
        const u16* qi = wi + (size_t)(n0 + r0 + lq) * DHn + qd*8;
#pragma unroll
        for (int c = 0; c < 2; ++c) {
            qfr[c] = *(const bf16x8*)(qr + c*32);
            qfi[c] = *(const bf16x8*)(qi + c*32);
            qfn[c] = bfneg(qfr[c]);
        }
    }

    float rm[4], rl[4];
#pragma unroll
    for (int p = 0; p < 4; ++p) { rm[p] = -1e30f; rl[p] = 0.f; }
    f32x4 Ore[4], Oim[4];
#pragma unroll
    for (int d = 0; d < 4; ++d) { Ore[d] = (f32x4)0.f; Oim[d] = (f32x4)0.f; }

    int sm = t >> 3, sdc = (t & 7) * 8;        // Kr/Ki: row m, dh-chunk
    int gdh = t & 63, gmc = t >> 6;            // Ktr/Kti: dh, m-chunk

    for (int kt = 0; kt < Nn/32; ++kt) {
        __syncthreads();   // prev tile's K/Kt/P reads done before restaging
        {
            const u16* pr = wr + (size_t)(kt*32 + sm) * DHn + sdc;
            const u16* pi = wi + (size_t)(kt*32 + sm) * DHn + sdc;
            *(bf16x8*)&Kr[sm][sdc] = *(const bf16x8*)pr;
            *(bf16x8*)&Ki[sm][sdc] = *(const bf16x8*)pi;
        }
        {
            const u16* gr = wr + (size_t)(kt*32 + gmc*8) * DHn + gdh;
            const u16* gi = wi + (size_t)(kt*32 + gmc*8) * DHn + gdh;
            bf16x8 tr, ti;
#pragma unroll
            for (int j = 0; j < 8; ++j) {
                tr[j] = (short)gr[(size_t)j * DHn];
                ti[j] = (short)gi[(size_t)j * DHn];
            }
            *(bf16x8*)&Ktr[gdh][gmc*8] = tr;
            *(bf16x8*)&Kti[gdh][gmc*8] = ti;
        }
        __syncthreads();   // staging visible

        float sre[2][4], sim[2][4], mag[2][4];
#pragma unroll
        for (int ct = 0; ct < 2; ++ct) {
            bf16x8 bkr[2], bki[2];
#pragma unroll
            for (int c = 0; c < 2; ++c) {
                bkr[c] = *(const bf16x8*)&Kr[ct*16 + lq][c*32 + qd*8];
                bki[c] = *(const bf16x8*)&Ki[ct*16 + lq][c*32 + qd*8];
            }
            f32x4 are = (f32x4)0.f, aim = (f32x4)0.f;
            __builtin_amdgcn_s_setprio(1);
            are = __builtin_amdgcn_mfma_f32_16x16x32_bf16(qfr[0], bkr[0], are, 0,0,0);
            are = __builtin_amdgcn_mfma_f32_16x16x32_bf16(qfi[0], bki[0], are, 0,0,0);
            are = __builtin_amdgcn_mfma_f32_16x16x32_bf16(qfr[1], bkr[1], are, 0,0,0);
            are = __builtin_amdgcn_mfma_f32_16x16x32_bf16(qfi[1], bki[1], are, 0,0,0);
            aim = __builtin_amdgcn_mfma_f32_16x16x32_bf16(qfi[0], bkr[0], aim, 0,0,0);
            aim = __builtin_amdgcn_mfma_f32_16x16x32_bf16(qfn[0], bki[0], aim, 0,0,0);
            aim = __builtin_amdgcn_mfma_f32_16x16x32_bf16(qfi[1], bkr[1], aim, 0,0,0);
            aim = __builtin_amdgcn_mfma_f32_16x16x32_bf16(qfn[1], bki[1], aim, 0,0,0);
            __builtin_amdgcn_s_setprio(0);
#pragma unroll
            for (int p = 0; p < 4; ++p) {
                float r = are[p] * SCALEf;
                float i = aim[p] * SCALEf;
                sre[ct][p] = r; sim[ct][p] = i;
                mag[ct][p] = sqrtf(r*r + i*i);
            }
        }

        float alpha[4];
#pragma unroll
        for (int p = 0; p < 4; ++p) {
            float pm = fmaxf(mag[0][p], mag[1][p]);
            pm = fmaxf(pm, __shfl_xor(pm, 1));
            pm = fmaxf(pm, __shfl_xor(pm, 2));
            pm = fmaxf(pm, __shfl_xor(pm, 4));
            pm = fmaxf(pm, __shfl_xor(pm, 8));
            float grow = pm - rm[p];
            if (grow > 8.f) {
                alpha[p] = __expf(-grow);
                rm[p] = pm;
            } else {
                alpha[p] = 1.f;
            }
        }
#pragma unroll
        for (int p = 0; p < 4; ++p) {
            float s = 0.f;
            int q = r0 + qd*4 + p;
#pragma unroll
            for (int ct = 0; ct < 2; ++ct) {
                float mg = mag[ct][p];
                float e = __expf(mg - rm[p]);
                s += e;
                float cr, ci;
                if (mg > 0.f) {
                    float f = e * __builtin_amdgcn_rcpf(mg);
                    cr = sre[ct][p] * f; ci = sim[ct][p] * f;
                } else { cr = e; ci = 0.f; }
                Pr[q][ct*16 + lq] = f2bf(cr);
                Pi[q][ct*16 + lq] = f2bf(ci);
            }
            s += __shfl_xor(s, 1);
            s += __shfl_xor(s, 2);
            s += __shfl_xor(s, 4);
            s += __shfl_xor(s, 8);
            rl[p] = rl[p]*alpha[p] + s;
        }

        if (alpha[0] != 1.f || alpha[1] != 1.f || alpha[2] != 1.f || alpha[3] != 1.f) {
#pragma unroll
            for (int d = 0; d < 4; ++d)
#pragma unroll
                for (int p = 0; p < 4; ++p) {
                    Ore[d][p] *= alpha[p];
                    Oim[d][p] *= alpha[p];
                }
        }
        __syncthreads();   // P writes visible (RESTORED: R17 replay divergence)

        bf16x8 par = *(const bf16x8*)&Pr[r0 + lq][qd*8];
        bf16x8 pai = *(const bf16x8*)&Pi[r0 + lq][qd*8];
        bf16x8 pan = bfneg(pai);
        __builtin_amdgcn_s_setprio(1);
#pragma unroll
        for (int d = 0; d < 4; ++d) {
            bf16x8 fr = *(const bf16x8*)&Ktr[d*16 + lq][qd*8];
            bf16x8 fi = *(const bf16x8*)&Kti[d*16 + lq][qd*8];
            Ore[d] = __builtin_amdgcn_mfma_f32_16x16x32_bf16(par, fr, Ore[d], 0,0,0);
            Ore[d] = __builtin_amdgcn_mfma_f32_16x16x32_bf16(pan, fi, Ore[d], 0,0,0);
            Oim[d] = __builtin_amdgcn_mfma_f32_16x16x32_bf16(par, fi, Oim[d], 0,0,0);
            Oim[d] = __builtin_amdgcn_mfma_f32_16x16x32_bf16(pai, fr, Oim[d], 0,0,0);
        }
        __builtin_amdgcn_s_setprio(0);
    }

#pragma unroll
    for (int p = 0; p < 4; ++p) {
        float inv = 1.f / rl[p];
        int n = n0 + r0 + qd*4 + p;
#pragma unroll
        for (int d = 0; d < 4; ++d) {
            int dh = d*16 + lq;
            size_t idx = ((size_t)b*Nn + n) * INNERn + h*DHn + dh;
            float vr = Ore[d][p] * inv;
            float vi = Oim[d][p] * inv;
            u16 hr = f2bf(vr);
            u16 hm = f2bf(vi);
            ah_re[idx] = hr; al_re[idx] = f2bf(vr - bf2f(hr));
            ah_im[idx] = hm; al_im[idx] = f2bf(vi - bf2f(hm));
        }
    }
}

// ---------------------------------------------------------------------------
// Kernel 3: output projection (real part only) via split-bf16 MFMA + bias.
// (R12/R14-verified)
// ---------------------------------------------------------------------------
__global__ __launch_bounds__(256) void gemm_out_mfma(
    const u16* __restrict__ ah_re, const u16* __restrict__ al_re,
    const u16* __restrict__ ah_im, const u16* __restrict__ al_im,
    const u16* __restrict__ oh_re, const u16* __restrict__ ol_re,
    const u16* __restrict__ oh_im, const u16* __restrict__ ol_im,
    const float* __restrict__ b_re, float* __restrict__ out)
{
    const int K = INNERn;
    __shared__ __align__(16) u16 Ahr[64][40], Alr[64][40], Ahi[64][40], Ali[64][40];
    __shared__ __align__(16) u16 Bhr[128][40], Blr[128][40], Bhi[128][40], Bli[128][40];

    int t    = threadIdx.x;
    int lane = t & 63;
    int wv   = t >> 6;
    int lq   = lane & 15, qd = lane >> 4;
    int wr   = wv >> 1,   wc = wv & 1;

    int id  = blockIdx.y * 8 + blockIdx.x;
    int swz = xcd_swz(id, 512);
    int m0 = (swz >> 3) * 64;
    int d0 = (swz & 7) * 128;

    int ar = t >> 2, ac = (t & 3) * 8;
    int br = t >> 1, bc = (t & 1) * 16;

    const u16* pA0 = ah_re + (size_t)(m0 + ar) * K + ac;
    const u16* pA1 = al_re + (size_t)(m0 + ar) * K + ac;
    const u16* pA2 = ah_im + (size_t)(m0 + ar) * K + ac;
    const u16* pA3 = al_im + (size_t)(m0 + ar) * K + ac;
    const u16* pB0 = oh_re + (size_t)(d0 + br) * K + bc;
    const u16* pB1 = ol_re + (size_t)(d0 + br) * K + bc;
    const u16* pB2 = oh_im + (size_t)(d0 + br) * K + bc;
    const u16* pB3 = ol_im + (size_t)(d0 + br) * K + bc;

    f32x4 accR[2][4];
#pragma unroll
    for (int i = 0; i < 2; ++i)
#pragma unroll
        for (int j = 0; j < 4; ++j) accR[i][j] = (f32x4)0.f;

    for (int k0 = 0; k0 < K; k0 += 32) {
        bf16x8 va0 = *(const bf16x8*)(pA0 + k0);
        bf16x8 va1 = *(const bf16x8*)(pA1 + k0);
        bf16x8 va2 = *(const bf16x8*)(pA2 + k0);
        bf16x8 va3 = *(const bf16x8*)(pA3 + k0);
        bf16x8 vb0a = *(const bf16x8*)(pB0 + k0), vb0b = *(const bf16x8*)(pB0 + k0 + 8);
        bf16x8 vb1a = *(const bf16x8*)(pB1 + k0), vb1b = *(const bf16x8*)(pB1 + k0 + 8);
        bf16x8 vb2a = *(const bf16x8*)(pB2 + k0), vb2b = *(const bf16x8*)(pB2 + k0 + 8);
        bf16x8 vb3a = *(const bf16x8*)(pB3 + k0), vb3b = *(const bf16x8*)(pB3 + k0 + 8);
        __syncthreads();
        *(bf16x8*)&Ahr[ar][ac] = va0;
        *(bf16x8*)&Alr[ar][ac] = va1;
        *(bf16x8*)&Ahi[ar][ac] = va2;
        *(bf16x8*)&Ali[ar][ac] = va3;
        *(bf16x8*)&Bhr[br][bc] = vb0a; *(bf16x8*)&Bhr[br][bc+8] = vb0b;
        *(bf16x8*)&Blr[br][bc] = vb1a; *(bf16x8*)&Blr[br][bc+8] = vb1b;
        *(bf16x8*)&Bhi[br][bc] = vb2a; *(bf16x8*)&Bhi[br][bc+8] = vb2b;
        *(bf16x8*)&Bli[br][bc] = vb3a; *(bf16x8*)&Bli[br][bc+8] = vb3b;
        __syncthreads();

        bf16x8 Arh[2], Arl[2], Anh[2], Anl[2];
#pragma unroll
        for (int rf = 0; rf < 2; ++rf) {
            int row = wr*32 + rf*16 + lq;
            Arh[rf] = *(const bf16x8*)&Ahr[row][qd*8];
            Arl[rf] = *(const bf16x8*)&Alr[row][qd*8];
            Anh[rf] = bfneg(*(const bf16x8*)&Ahi[row][qd*8]);
            Anl[rf] = bfneg(*(const bf16x8*)&Ali[row][qd*8]);
        }
#pragma unroll
        for (int cf = 0; cf < 4; ++cf) {
            int col = wc*64 + cf*16 + lq;
            bf16x8 Brh = *(const bf16x8*)&Bhr[col][qd*8];
            bf16x8 Brl = *(const bf16x8*)&Blr[col][qd*8];
            bf16x8 Bih = *(const bf16x8*)&Bhi[col][qd*8];
            bf16x8 Bil = *(const bf16x8*)&Bli[col][qd*8];
#pragma unroll
            for (int rf = 0; rf < 2; ++rf) {
                MFMA16(accR[rf][cf], Arh[rf], Brh);
                MFMA16(accR[rf][cf], Arh[rf], Brl);
                MFMA16(accR[rf][cf], Arl[rf], Brh);
                MFMA16(accR[rf][cf], Anh[rf], Bih);
                MFMA16(accR[rf][cf], Anh[rf], Bil);
                MFMA16(accR[rf][cf], Anl[rf], Bih);
            }
        }
    }

#pragma unroll
    for (int rf = 0; rf < 2; ++rf)
#pragma unroll
        for (int cf = 0; cf < 4; ++cf)
#pragma unroll
            for (int p = 0; p < 4; ++p) {
                int m = m0 + wr*32 + rf*16 + qd*4 + p;
                int d = d0 + wc*64 + cf*16 + lq;
                out[(size_t)m * Dn + d] = accR[rf][cf][p] + b_re[d];
            }
}

// ---------------------------------------------------------------------------
// Workspace layout (u16 units), 64 MB total (unchanged).
// ---------------------------------------------------------------------------
extern "C" void kernel_launch(void* const* d_in, const int* in_sizes, int n_in,
                              void* d_out, int out_size, void* d_ws, size_t ws_size,
                              hipStream_t stream) {
    const float* x_re  = (const float*)d_in[0];
    const float* x_im  = (const float*)d_in[1];
    const float* wq_re = (const float*)d_in[2];
    const float* wq_im = (const float*)d_in[3];
    const float* wo_re = (const float*)d_in[4];
    const float* wo_im = (const float*)d_in[5];
    const float* bo_re = (const float*)d_in[6];

    const size_t M4 = (size_t)Bn * Nn * INNERn;   // 4M
    const size_t M1 = (size_t)INNERn * Dn;        // 1M

    u16* ws = (u16*)d_ws;
    u16* xh_re = ws;
    u16* xl_re = ws + M4;
    u16* xh_im = ws + 2*M4;
    u16* xl_im = ws + 3*M4;
    u16* wqh_re = ws + 4*M4;
    u16* wql_re = wqh_re + M1;
    u16* wqh_im = wql_re + M1;
    u16* wql_im = wqh_im + M1;
    u16* woh_re = wql_im + M1;
    u16* wol_re = woh_re + M1;
    u16* woh_im = wol_re + M1;
    u16* wol_im = woh_im + M1;
    u16* w_re16 = wol_im + M1;
    u16* w_im16 = w_re16 + M4;
    // attn output aliases the (dead after gemm_qkv) x hi/lo region
    u16* ah_re = xh_re;
    u16* al_re = xl_re;
    u16* ah_im = xh_im;
    u16* al_im = xl_im;

    {
        dim3 grid(2048, 6);
        split6<<<grid, 256, 0, stream>>>(x_re, x_im, wq_re, wq_im, wo_re, wo_im,
            xh_re, xl_re, xh_im, xl_im,
            wqh_re, wql_re, wqh_im, wql_im,
            woh_re, wol_re, woh_im, wol_im);
    }
    {
        dim3 grid(INNERn / 128, (Bn * Nn) / 64);
        gemm_qkv_mfma<<<grid, 256, 0, stream>>>(
            xh_re, xl_re, xh_im, xl_im,
            wqh_re, wql_re, wqh_im, wql_im,
            w_re16, w_im16);
    }
    {
        dim3 grid(Nn / 64, Bn * Hn);
        attn_mfma<<<grid, 256, 0, stream>>>(w_re16, w_im16,
                                            ah_re, al_re, ah_im, al_im);
    }
    {
        dim3 grid(Dn / 128, (Bn * Nn) / 64);
        gemm_out_mfma<<<grid, 256, 0, stream>>>(
            ah_re, al_re, ah_im, al_im,
            woh_re, wol_re, woh_im, wol_im,
            bo_re, (float*)d_out);
    }
}